// Round 12
// baseline (413.870 us; speedup 1.0000x reference)
//
#include <hip/hip_runtime.h>

typedef _Float16 f16;
typedef _Float16 f16x8 __attribute__((ext_vector_type(8)));
typedef _Float16 f16x4 __attribute__((ext_vector_type(4)));
typedef float f32x4 __attribute__((ext_vector_type(4)));

#define B_ 512
#define L_ 512
#define Cc_ 64
#define Ct_ 16
#define Co_ 8
#define H_ 128
#define IN_ 88
#define KP 96       // padded K for MFMA
#define G3 384      // 3*H
#define R_ 16       // batch rows per scan block / gemm tile

#define L2E  1.44269504088896f   // log2(e)
#define L2E2 2.88539008177793f   // 2*log2(e)

// Fragment-ordered x: inpF[bg][l][ks=0..2][c*4+q][j=0..7] (f16), 1536 f16 per (bg,l).
//   B-frag element (batch c, k=32ks+8q+j). Norm block (batch b) writes 64B chunks
//   (q=0..3 contiguous); scan/gemm wave reads 1KB contiguous per ks.

// ---------------- K1: prep (blocks 0..145) + time-norm + concat -> inpF ------------------
__global__ __launch_bounds__(256) void k_norm(
        const float* __restrict__ cov, const float* __restrict__ tr, const float* __restrict__ oc,
        const float* __restrict__ g_t, const float* __restrict__ bt,
        const float* __restrict__ g_o, const float* __restrict__ bo,
        const float* __restrict__ g_c, const float* __restrict__ bc,
        const float* __restrict__ Wih, const float* __restrict__ bih,
        const float* __restrict__ bhh,
        f16* __restrict__ inpF, f16* __restrict__ WAf, float* __restrict__ biasF) {
    int b = blockIdx.x, t = threadIdx.x;

    // ---- merged k_prep: W_ih -> A-fragment order (scaled); bias (b_hh folded, scaled) ----
    if (b < 146) {
        int idx = b * 256 + t;
        if (idx < G3 * KP) {                       // 36864 WAf elements
            int n0 = idx / 1536;
            int rem = idx - n0 * 1536;
            int ks = rem >> 9;
            int rem2 = rem & 511;
            int lane = rem2 >> 3, j = rem2 & 7;
            int unit = n0 * 16 + (lane & 15);
            int k = ((lane >> 4) << 3) + 32 * ks + j;
            float s = (n0 < 16) ? L2E : L2E2;
            WAf[idx] = (k < IN_) ? (f16)(Wih[unit * IN_ + k] * s) : (f16)0.f;
        } else if (idx < G3 * KP + G3) {           // 384 biases (unit-indexed)
            int u = idx - G3 * KP;
            biasF[u] = (u < 256) ? (bih[u] + bhh[u]) * L2E : bih[u] * L2E2;
        }
    }

    __shared__ float ps[256], ps2[256];
    __shared__ float sc[88], sh[88];   // concat order: t[0:16), o[16:24), c[24:88)

    { // covariates, C=64, 4 l-groups
        int c = t & 63, lg = t >> 6;
        const float* p = cov + (size_t)b * L_ * Cc_ + c;
        float s = 0.f, s2 = 0.f;
        for (int i = lg; i < L_; i += 4) { float v = p[(size_t)i * Cc_]; s += v; s2 += v * v; }
        ps[t] = s; ps2[t] = s2; __syncthreads();
        if (t < 64) {
            float S = 0.f, S2 = 0.f;
            for (int g = 0; g < 4; g++) { S += ps[t + 64 * g]; S2 += ps2[t + 64 * g]; }
            float m = S * (1.f / L_), v = S2 * (1.f / L_) - m * m;
            float inv = rsqrtf(v + 1e-5f);
            float gg = g_c[t] * inv;
            sc[24 + t] = gg; sh[24 + t] = bc[t] - m * gg;
        }
        __syncthreads();
    }
    { // treatments, C=16, 16 l-groups
        int c = t & 15, lg = t >> 4;
        const float* p = tr + (size_t)b * L_ * Ct_ + c;
        float s = 0.f, s2 = 0.f;
        for (int i = lg; i < L_; i += 16) { float v = p[(size_t)i * Ct_]; s += v; s2 += v * v; }
        ps[t] = s; ps2[t] = s2; __syncthreads();
        if (t < 16) {
            float S = 0.f, S2 = 0.f;
            for (int g = 0; g < 16; g++) { S += ps[t + 16 * g]; S2 += ps2[t + 16 * g]; }
            float m = S * (1.f / L_), v = S2 * (1.f / L_) - m * m;
            float inv = rsqrtf(v + 1e-5f);
            float gg = g_t[t] * inv;
            sc[t] = gg; sh[t] = bt[t] - m * gg;
        }
        __syncthreads();
    }
    { // outcomes, C=8, 32 l-groups
        int c = t & 7, lg = t >> 3;
        const float* p = oc + (size_t)b * L_ * Co_ + c;
        float s = 0.f, s2 = 0.f;
        for (int i = lg; i < L_; i += 32) { float v = p[(size_t)i * Co_]; s += v; s2 += v * v; }
        ps[t] = s; ps2[t] = s2; __syncthreads();
        if (t < 8) {
            float S = 0.f, S2 = 0.f;
            for (int g = 0; g < 32; g++) { S += ps[t + 8 * g]; S2 += ps2[t + 8 * g]; }
            float m = S * (1.f / L_), v = S2 * (1.f / L_) - m * m;
            float inv = rsqrtf(v + 1e-5f);
            float gg = g_o[t] * inv;
            sc[16 + t] = gg; sh[16 + t] = bo[t] - m * gg;
        }
        __syncthreads();
    }
    // phase B (vectorized): thread-iter = (l, f); 8 consecutive channels k0 = 8f.
    // Concat boundaries (16, 24) are multiples of 8 -> each chunk is single-source.
    // 2x float4 loads + 1 f16x8 store. Write: [l][ks=f>>2][ (b&15)*4 + (f&3) ][8].
    const int cq = b & 15;
    f16* outp = inpF + (size_t)(b >> 4) * L_ * 1536;
    for (int idx = t; idx < L_ * 12; idx += 256) {
        int l = idx / 12, f = idx - l * 12;
        int k0 = f * 8;
        f16x8 st;
        #pragma unroll
        for (int j = 0; j < 8; j++) st[j] = (f16)0.f;
        if (k0 < IN_) {
            const float* src;
            if (k0 < 16)      src = tr  + ((size_t)b * L_ + l) * Ct_ + k0;
            else if (k0 < 24) src = oc  + ((size_t)b * L_ + l) * Co_ + (k0 - 16);
            else              src = cov + ((size_t)b * L_ + l) * Cc_ + (k0 - 24);
            f32x4 v0 = *(const f32x4*)(src);
            f32x4 v1 = *(const f32x4*)(src + 4);
            #pragma unroll
            for (int j = 0; j < 4; j++) st[j]     = (f16)(v0[j] * sc[k0 + j]     + sh[k0 + j]);
            #pragma unroll
            for (int j = 0; j < 4; j++) st[4 + j] = (f16)(v1[j] * sc[k0 + 4 + j] + sh[k0 + 4 + j]);
        }
        int ks = f >> 2, q = f & 3;
        *(f16x8*)(outp + ((size_t)l * 3 + ks) * 512 + (cq * 4 + q) * 8) = st;
    }
}

// ============== FUSED SCAN: gi computed in-register (no giF tensor at all). ==============
// One block = 16 batch rows, 8 waves (2/SIMD). Wave w owns units [16w,16w+16) of each
// gate. acc chain: acc = bias; acc += W_ih x (3 MFMA); acc += W_hh h (4 MFMA).
// x-loads now wave-contiguous 1KB (fragment-ordered inpF).
__global__ __launch_bounds__(512, 1) void k_scan_f(
        const f16* __restrict__ inpF, const f16* __restrict__ WAf,
        const float* __restrict__ biasF,
        const float* __restrict__ Whh, const float* __restrict__ bhh,
        float* __restrict__ outA, float* __restrict__ outB) {
    const int t = threadIdx.x;
    const int w = t >> 6;          // wave 0..7
    const int lane = t & 63;
    const int c = lane & 15;       // batch row within tile
    const int q = lane >> 4;       // 0..3
    const int q8 = q * 8;
    const int uD = 16 * w + 4 * q; // unit base within a gate block
    const int bg = blockIdx.x;     // batch group (16 rows)

    __shared__ f16 hb0[R_ * H_];   // 4KB each, swizzled [b][k^((b&15)<<3)]
    __shared__ f16 hb1[R_ * H_];

    // persistent W_hh A-fragments: unit = 16w + c, k = q8 + 32ks + j  (f32 -> f16, scaled)
    f16x8 WA[3][4];
    #pragma unroll
    for (int g = 0; g < 3; g++) {
        float s = (g < 2) ? L2E : L2E2;
        #pragma unroll
        for (int ks = 0; ks < 4; ks++) {
            const float* wp = Whh + (size_t)(g * H_ + 16 * w + c) * H_ + q8 + 32 * ks;
            f16x8 v;
            #pragma unroll
            for (int j = 0; j < 8; j++) v[j] = (f16)(wp[j] * s);
            WA[g][ks] = v;
        }
    }
    // persistent W_ih A-fragments (pre-scaled in WAf): tiles n0 = g*8 + w, ks = 0..2
    const f16x8* wa8 = (const f16x8*)WAf;
    f16x8 WI[3][3];
    #pragma unroll
    for (int g = 0; g < 3; g++)
        #pragma unroll
        for (int ks = 0; ks < 3; ks++)
            WI[g][ks] = wa8[(size_t)((g * 8 + w) * 3 + ks) * 64 + lane];

    // per-lane accumulator-init biases (unit-indexed n0*16 + 4q)
    const f32x4 bR   = *(const f32x4*)(biasF + (0 * 8 + w) * 16 + 4 * q);
    const f32x4 bZ   = *(const f32x4*)(biasF + (1 * 8 + w) * 16 + 4 * q);
    const f32x4 bGn  = *(const f32x4*)(biasF + (2 * 8 + w) * 16 + 4 * q);
    const f32x4 bHn  = { L2E2 * bhh[2 * H_ + uD + 0], L2E2 * bhh[2 * H_ + uD + 1],
                         L2E2 * bhh[2 * H_ + uD + 2], L2E2 * bhh[2 * H_ + uD + 3] };

    for (int i = t; i < R_ * H_; i += 512) hb0[i] = (f16)0.f;
    float hp0 = 0.f, hp1 = 0.f, hp2 = 0.f, hp3 = 0.f;

    // ---- coalesced output staging: thread -> (row, 4 contiguous units) ----
    const int orow = t >> 5;               // 0..15 (block-local row)
    const int oe4  = (t & 31) * 4;         // unit base 0..124
    const int oswz = (orow & 15) << 3;
    const int grow = bg * R_ + orow;
    float* op; size_t ost;
    if (oe4 < Co_) { op = outA + (size_t)grow * L_ * Co_ + oe4;            ost = Co_; }
    else           { op = outB + (size_t)grow * L_ * (H_ - Co_) + (oe4 - Co_); ost = H_ - Co_; }

    const int swzm = (c & 15) << 3;             // full-width XOR swizzle (f16 idx bits 3..6)

    // x fragment pointer: fragment-ordered -> 1KB contiguous per (l,ks), 16B per lane
    const f16* xp = inpF + (size_t)bg * L_ * 1536 + (c * 4 + q) * 8;

    // preload x[0] into E buffers
    f16x8 x0e = *(const f16x8*)(xp);
    f16x8 x1e = *(const f16x8*)(xp + 512);
    f16x8 x2e = *(const f16x8*)(xp + 1024);
    f16x8 x0o, x1o, x2o;

    __syncthreads();

#define GRU_STEP(HCUR, HNEXT, X0, X1, X2, DOSTAGE)                                  \
    {                                                                               \
        if (DOSTAGE) {  /* store h_out(prev step), coalesced, f16-rounded */        \
            f16x4 hv = *(const f16x4*)(HCUR + orow * H_ + (oe4 ^ oswz));            \
            f32x4 ov = {(float)hv[0], (float)hv[1], (float)hv[2], (float)hv[3]};    \
            *(f32x4*)op = ov;                                                       \
            op += ost;                                                              \
        }                                                                           \
        f16x8 hB0 = *(const f16x8*)(HCUR + c * H_ + ((q8 +  0) ^ swzm));            \
        f16x8 hB1 = *(const f16x8*)(HCUR + c * H_ + ((q8 + 32) ^ swzm));            \
        f16x8 hB2 = *(const f16x8*)(HCUR + c * H_ + ((q8 + 64) ^ swzm));            \
        f16x8 hB3 = *(const f16x8*)(HCUR + c * H_ + ((q8 + 96) ^ swzm));            \
        f32x4 aR = bR, aZ = bZ, aG = bGn, aH = bHn;                                 \
        /* gi part: x-MFMAs (no hB dependency -> fills DS latency) */               \
        aR = __builtin_amdgcn_mfma_f32_16x16x32_f16(WI[0][0], X0, aR, 0, 0, 0);     \
        aZ = __builtin_amdgcn_mfma_f32_16x16x32_f16(WI[1][0], X0, aZ, 0, 0, 0);     \
        aG = __builtin_amdgcn_mfma_f32_16x16x32_f16(WI[2][0], X0, aG, 0, 0, 0);     \
        aR = __builtin_amdgcn_mfma_f32_16x16x32_f16(WI[0][1], X1, aR, 0, 0, 0);     \
        aZ = __builtin_amdgcn_mfma_f32_16x16x32_f16(WI[1][1], X1, aZ, 0, 0, 0);     \
        aG = __builtin_amdgcn_mfma_f32_16x16x32_f16(WI[2][1], X1, aG, 0, 0, 0);     \
        aR = __builtin_amdgcn_mfma_f32_16x16x32_f16(WI[0][2], X2, aR, 0, 0, 0);     \
        aZ = __builtin_amdgcn_mfma_f32_16x16x32_f16(WI[1][2], X2, aZ, 0, 0, 0);     \
        aG = __builtin_amdgcn_mfma_f32_16x16x32_f16(WI[2][2], X2, aG, 0, 0, 0);     \
        /* h part */                                                                \
        aR = __builtin_amdgcn_mfma_f32_16x16x32_f16(WA[0][0], hB0, aR, 0, 0, 0);    \
        aZ = __builtin_amdgcn_mfma_f32_16x16x32_f16(WA[1][0], hB0, aZ, 0, 0, 0);    \
        aH = __builtin_amdgcn_mfma_f32_16x16x32_f16(WA[2][0], hB0, aH, 0, 0, 0);    \
        aR = __builtin_amdgcn_mfma_f32_16x16x32_f16(WA[0][1], hB1, aR, 0, 0, 0);    \
        aZ = __builtin_amdgcn_mfma_f32_16x16x32_f16(WA[1][1], hB1, aZ, 0, 0, 0);    \
        aH = __builtin_amdgcn_mfma_f32_16x16x32_f16(WA[2][1], hB1, aH, 0, 0, 0);    \
        aR = __builtin_amdgcn_mfma_f32_16x16x32_f16(WA[0][2], hB2, aR, 0, 0, 0);    \
        aZ = __builtin_amdgcn_mfma_f32_16x16x32_f16(WA[1][2], hB2, aZ, 0, 0, 0);    \
        aH = __builtin_amdgcn_mfma_f32_16x16x32_f16(WA[2][2], hB2, aH, 0, 0, 0);    \
        aR = __builtin_amdgcn_mfma_f32_16x16x32_f16(WA[0][3], hB3, aR, 0, 0, 0);    \
        aZ = __builtin_amdgcn_mfma_f32_16x16x32_f16(WA[1][3], hB3, aZ, 0, 0, 0);    \
        aH = __builtin_amdgcn_mfma_f32_16x16x32_f16(WA[2][3], hB3, aH, 0, 0, 0);    \
        float rg0 = __builtin_amdgcn_rcpf(1.f + __builtin_amdgcn_exp2f(-aR[0]));    \
        float rg1 = __builtin_amdgcn_rcpf(1.f + __builtin_amdgcn_exp2f(-aR[1]));    \
        float rg2 = __builtin_amdgcn_rcpf(1.f + __builtin_amdgcn_exp2f(-aR[2]));    \
        float rg3 = __builtin_amdgcn_rcpf(1.f + __builtin_amdgcn_exp2f(-aR[3]));    \
        float zg0 = __builtin_amdgcn_rcpf(1.f + __builtin_amdgcn_exp2f(-aZ[0]));    \
        float zg1 = __builtin_amdgcn_rcpf(1.f + __builtin_amdgcn_exp2f(-aZ[1]));    \
        float zg2 = __builtin_amdgcn_rcpf(1.f + __builtin_amdgcn_exp2f(-aZ[2]));    \
        float zg3 = __builtin_amdgcn_rcpf(1.f + __builtin_amdgcn_exp2f(-aZ[3]));    \
        float tn0 = fmaf(rg0, aH[0], aG[0]);                                        \
        float tn1 = fmaf(rg1, aH[1], aG[1]);                                        \
        float tn2 = fmaf(rg2, aH[2], aG[2]);                                        \
        float tn3 = fmaf(rg3, aH[3], aG[3]);                                        \
        float ng0 = fmaf(2.f, __builtin_amdgcn_rcpf(1.f + __builtin_amdgcn_exp2f(-tn0)), -1.f); \
        float ng1 = fmaf(2.f, __builtin_amdgcn_rcpf(1.f + __builtin_amdgcn_exp2f(-tn1)), -1.f); \
        float ng2 = fmaf(2.f, __builtin_amdgcn_rcpf(1.f + __builtin_amdgcn_exp2f(-tn2)), -1.f); \
        float ng3 = fmaf(2.f, __builtin_amdgcn_rcpf(1.f + __builtin_amdgcn_exp2f(-tn3)), -1.f); \
        hp0 = fmaf(zg0, hp0 - ng0, ng0);                                            \
        hp1 = fmaf(zg1, hp1 - ng1, ng1);                                            \
        hp2 = fmaf(zg2, hp2 - ng2, ng2);                                            \
        hp3 = fmaf(zg3, hp3 - ng3, ng3);                                            \
        f16x4 hv16 = {(f16)hp0, (f16)hp1, (f16)hp2, (f16)hp3};                      \
        *(f16x4*)(HNEXT + c * H_ + (uD ^ swzm)) = hv16;                             \
    }

    for (int l = 0; l < L_; l += 2) {
        // ---- even step l: read hb0, write hb1; prefetch x[l+1] ----
        {
            const f16* xn = xp + (size_t)(l + 1) * 1536;
            x0o = *(const f16x8*)(xn);
            x1o = *(const f16x8*)(xn + 512);
            x2o = *(const f16x8*)(xn + 1024);
        }
        GRU_STEP(hb0, hb1, x0e, x1e, x2e, (l > 0))
        __syncthreads();

        // ---- odd step l+1: read hb1, write hb0; prefetch x[l+2] ----
        {
            int lp = (l + 2 < L_) ? (l + 2) : (L_ - 1);   // clamp: last reload unused
            const f16* xn = xp + (size_t)lp * 1536;
            x0e = *(const f16x8*)(xn);
            x1e = *(const f16x8*)(xn + 512);
            x2e = *(const f16x8*)(xn + 1024);
        }
        GRU_STEP(hb1, hb0, x0o, x1o, x2o, true)
        __syncthreads();
    }
#undef GRU_STEP

    // final output: h_out(L-1) sits in hb0, barrier already passed
    {
        f16x4 hv = *(const f16x4*)(hb0 + orow * H_ + (oe4 ^ oswz));
        f32x4 ov = {(float)hv[0], (float)hv[1], (float)hv[2], (float)hv[3]};
        *(f32x4*)op = ov;
    }
}

// ============== FALLBACK path (small ws): gemm + gi-reading scan. ==============
__global__ __launch_bounds__(256) void k_gemm(
        const f16* __restrict__ inpF, const f16* __restrict__ WAf,
        const float* __restrict__ biasF, f16* __restrict__ giF) {
    const int g0 = blockIdx.x >> 7;
    const int l  = ((blockIdx.x & 127) << 2) + (threadIdx.x >> 6);
    const int lane = threadIdx.x & 63;
    const int c = lane & 15, q = lane >> 4;
    const f16* bp = inpF + ((size_t)g0 * L_ + l) * 1536 + (c * 4 + q) * 8;
    f16x8 x0 = *(const f16x8*)(bp);
    f16x8 x1 = *(const f16x8*)(bp + 512);
    f16x8 x2 = *(const f16x8*)(bp + 1024);
    const f16x8* wa = (const f16x8*)WAf;
    f16* gout = giF + ((size_t)g0 * L_ + l) * 6144 + q * 64 + c * 4;
    #pragma unroll 4
    for (int n0 = 0; n0 < 24; n0++) {
        f16x8 a0 = wa[(n0 * 3 + 0) * 64 + lane];
        f16x8 a1 = wa[(n0 * 3 + 1) * 64 + lane];
        f16x8 a2 = wa[(n0 * 3 + 2) * 64 + lane];
        f32x4 acc = *(const f32x4*)(biasF + n0 * 16 + q * 4);
        acc = __builtin_amdgcn_mfma_f32_16x16x32_f16(a0, x0, acc, 0, 0, 0);
        acc = __builtin_amdgcn_mfma_f32_16x16x32_f16(a1, x1, acc, 0, 0, 0);
        acc = __builtin_amdgcn_mfma_f32_16x16x32_f16(a2, x2, acc, 0, 0, 0);
        f16x4 st = {(f16)acc[0], (f16)acc[1], (f16)acc[2], (f16)acc[3]};
        *(f16x4*)(gout + n0 * 256) = st;
    }
}

__global__ __launch_bounds__(512, 2) void k_scan(
        const f16* __restrict__ giF, const float* __restrict__ Whh,
        const float* __restrict__ bhh, float* __restrict__ outA, float* __restrict__ outB,
        int rowBase) {
    const int t = threadIdx.x;
    const int w = t >> 6;
    const int lane = t & 63;
    const int c = lane & 15;
    const int q = lane >> 4;
    const int q8 = q * 8;
    const int uD = 16 * w + q * 4;
    __shared__ f16 hb0[R_ * H_];
    __shared__ f16 hb1[R_ * H_];
    f16x8 WA[3][4];
    #pragma unroll
    for (int g = 0; g < 3; g++) {
        float s = (g < 2) ? L2E : L2E2;
        #pragma unroll
        for (int ks = 0; ks < 4; ks++) {
            const float* wp = Whh + (size_t)(g * H_ + 16 * w + c) * H_ + q8 + 32 * ks;
            f16x8 v;
            #pragma unroll
            for (int j = 0; j < 8; j++) v[j] = (f16)(wp[j] * s);
            WA[g][ks] = v;
        }
    }
    const f32x4 bN = { L2E2 * bhh[2 * H_ + uD + 0], L2E2 * bhh[2 * H_ + uD + 1],
                       L2E2 * bhh[2 * H_ + uD + 2], L2E2 * bhh[2 * H_ + uD + 3] };
    for (int i = t; i < R_ * H_; i += 512) hb0[i] = (f16)0.f;
    float hp0 = 0.f, hp1 = 0.f, hp2 = 0.f, hp3 = 0.f;
    const int orow = t >> 5;
    const int oe4  = (t & 31) * 4;
    const int oswz = (orow & 15) << 3;
    const int grow = rowBase + blockIdx.x * R_ + orow;
    float* op; size_t ost;
    if (oe4 < Co_) { op = outA + (size_t)grow * L_ * Co_ + oe4;            ost = Co_; }
    else           { op = outB + (size_t)grow * L_ * (H_ - Co_) + (oe4 - Co_); ost = H_ - Co_; }
    const int swzm = (c & 15) << 3;
    const f16* gbase = giF + (size_t)blockIdx.x * L_ * 24 * 256 + w * 256 + q * 64 + c * 4;
    f16x4 gRe = *(const f16x4*)(gbase + 0 * 2048);
    f16x4 gZe = *(const f16x4*)(gbase + 1 * 2048);
    f16x4 gNe = *(const f16x4*)(gbase + 2 * 2048);
    f16x4 gRo, gZo, gNo;
    __syncthreads();
#define GRU_STEP(HCUR, HNEXT, GR, GZ, GN, DOSTAGE)                                  \
    {                                                                               \
        if (DOSTAGE) {                                                              \
            f16x4 hv = *(const f16x4*)(HCUR + orow * H_ + (oe4 ^ oswz));            \
            f32x4 ov = {(float)hv[0], (float)hv[1], (float)hv[2], (float)hv[3]};    \
            *(f32x4*)op = ov;                                                       \
            op += ost;                                                              \
        }                                                                           \
        f16x8 hB0 = *(const f16x8*)(HCUR + c * H_ + ((q8 +  0) ^ swzm));            \
        f16x8 hB1 = *(const f16x8*)(HCUR + c * H_ + ((q8 + 32) ^ swzm));            \
        f16x8 hB2 = *(const f16x8*)(HCUR + c * H_ + ((q8 + 64) ^ swzm));            \
        f16x8 hB3 = *(const f16x8*)(HCUR + c * H_ + ((q8 + 96) ^ swzm));            \
        f32x4 aR = {(float)GR[0], (float)GR[1], (float)GR[2], (float)GR[3]};        \
        f32x4 aZ = {(float)GZ[0], (float)GZ[1], (float)GZ[2], (float)GZ[3]};        \
        f32x4 aN = bN;                                                              \
        aR = __builtin_amdgcn_mfma_f32_16x16x32_f16(WA[0][0], hB0, aR, 0, 0, 0);    \
        aZ = __builtin_amdgcn_mfma_f32_16x16x32_f16(WA[1][0], hB0, aZ, 0, 0, 0);    \
        aN = __builtin_amdgcn_mfma_f32_16x16x32_f16(WA[2][0], hB0, aN, 0, 0, 0);    \
        aR = __builtin_amdgcn_mfma_f32_16x16x32_f16(WA[0][1], hB1, aR, 0, 0, 0);    \
        aZ = __builtin_amdgcn_mfma_f32_16x16x32_f16(WA[1][1], hB1, aZ, 0, 0, 0);    \
        aN = __builtin_amdgcn_mfma_f32_16x16x32_f16(WA[2][1], hB1, aN, 0, 0, 0);    \
        aR = __builtin_amdgcn_mfma_f32_16x16x32_f16(WA[0][2], hB2, aR, 0, 0, 0);    \
        aZ = __builtin_amdgcn_mfma_f32_16x16x32_f16(WA[1][2], hB2, aZ, 0, 0, 0);    \
        aN = __builtin_amdgcn_mfma_f32_16x16x32_f16(WA[2][2], hB2, aN, 0, 0, 0);    \
        aR = __builtin_amdgcn_mfma_f32_16x16x32_f16(WA[0][3], hB3, aR, 0, 0, 0);    \
        aZ = __builtin_amdgcn_mfma_f32_16x16x32_f16(WA[1][3], hB3, aZ, 0, 0, 0);    \
        aN = __builtin_amdgcn_mfma_f32_16x16x32_f16(WA[2][3], hB3, aN, 0, 0, 0);    \
        float rg0 = __builtin_amdgcn_rcpf(1.f + __builtin_amdgcn_exp2f(-aR[0]));    \
        float rg1 = __builtin_amdgcn_rcpf(1.f + __builtin_amdgcn_exp2f(-aR[1]));    \
        float rg2 = __builtin_amdgcn_rcpf(1.f + __builtin_amdgcn_exp2f(-aR[2]));    \
        float rg3 = __builtin_amdgcn_rcpf(1.f + __builtin_amdgcn_exp2f(-aR[3]));    \
        float zg0 = __builtin_amdgcn_rcpf(1.f + __builtin_amdgcn_exp2f(-aZ[0]));    \
        float zg1 = __builtin_amdgcn_rcpf(1.f + __builtin_amdgcn_exp2f(-aZ[1]));    \
        float zg2 = __builtin_amdgcn_rcpf(1.f + __builtin_amdgcn_exp2f(-aZ[2]));    \
        float zg3 = __builtin_amdgcn_rcpf(1.f + __builtin_amdgcn_exp2f(-aZ[3]));    \
        float tn0 = fmaf(rg0, aN[0], (float)GN[0]);                                 \
        float tn1 = fmaf(rg1, aN[1], (float)GN[1]);                                 \
        float tn2 = fmaf(rg2, aN[2], (float)GN[2]);                                 \
        float tn3 = fmaf(rg3, aN[3], (float)GN[3]);                                 \
        float ng0 = fmaf(2.f, __builtin_amdgcn_rcpf(1.f + __builtin_amdgcn_exp2f(-tn0)), -1.f); \
        float ng1 = fmaf(2.f, __builtin_amdgcn_rcpf(1.f + __builtin_amdgcn_exp2f(-tn1)), -1.f); \
        float ng2 = fmaf(2.f, __builtin_amdgcn_rcpf(1.f + __builtin_amdgcn_exp2f(-tn2)), -1.f); \
        float ng3 = fmaf(2.f, __builtin_amdgcn_rcpf(1.f + __builtin_amdgcn_exp2f(-tn3)), -1.f); \
        hp0 = fmaf(zg0, hp0 - ng0, ng0);                                            \
        hp1 = fmaf(zg1, hp1 - ng1, ng1);                                            \
        hp2 = fmaf(zg2, hp2 - ng2, ng2);                                            \
        hp3 = fmaf(zg3, hp3 - ng3, ng3);                                            \
        f16x4 hv16 = {(f16)hp0, (f16)hp1, (f16)hp2, (f16)hp3};                      \
        *(f16x4*)(HNEXT + c * H_ + (uD ^ swzm)) = hv16;                             \
    }
    for (int l = 0; l < L_; l += 2) {
        {
            const f16* gn = gbase + (size_t)(l + 1) * 6144;
            gRo = *(const f16x4*)(gn + 0 * 2048);
            gZo = *(const f16x4*)(gn + 1 * 2048);
            gNo = *(const f16x4*)(gn + 2 * 2048);
        }
        GRU_STEP(hb0, hb1, gRe, gZe, gNe, (l > 0))
        __syncthreads();
        {
            int lp = (l + 2 < L_) ? (l + 2) : (L_ - 1);
            const f16* gn = gbase + (size_t)lp * 6144;
            gRe = *(const f16x4*)(gn + 0 * 2048);
            gZe = *(const f16x4*)(gn + 1 * 2048);
            gNe = *(const f16x4*)(gn + 2 * 2048);
        }
        GRU_STEP(hb1, hb0, gRo, gZo, gNo, true)
        __syncthreads();
    }
#undef GRU_STEP
    {
        f16x4 hv = *(const f16x4*)(hb0 + orow * H_ + (oe4 ^ oswz));
        f32x4 ov = {(float)hv[0], (float)hv[1], (float)hv[2], (float)hv[3]};
        *(f32x4*)op = ov;
    }
}

// ---------------- launch ----------------
extern "C" void kernel_launch(void* const* d_in, const int* in_sizes, int n_in,
                              void* d_out, int out_size, void* d_ws, size_t ws_size,
                              hipStream_t stream) {
    (void)in_sizes; (void)n_in;
    const float* cov = (const float*)d_in[0];
    const float* tr  = (const float*)d_in[1];
    const float* oc  = (const float*)d_in[2];
    const float* Wih = (const float*)d_in[3];
    const float* Whh = (const float*)d_in[4];
    const float* bih = (const float*)d_in[5];
    const float* bhh = (const float*)d_in[6];
    const float* g_t = (const float*)d_in[7];
    const float* bt  = (const float*)d_in[8];
    const float* g_o = (const float*)d_in[9];
    const float* bo  = (const float*)d_in[10];
    const float* g_c = (const float*)d_in[11];
    const float* bc  = (const float*)d_in[12];

    float* outA = (float*)d_out;
    float* outB = (float*)d_out + (size_t)B_ * L_ * Co_;

    // workspace: [WAf 72KB | biasF 1.5KB | pad to 128KB | inpF 50.3MB (direct) / giF (fallback)]
    f16*   WAf   = (f16*)d_ws;
    float* biasF = (float*)((char*)d_ws + 73728);

    size_t outBytes = (size_t)out_size * 4;
    size_t ihBytes  = (size_t)B_ * L_ * KP * 2;        // 50.3 MB

    bool direct = ws_size >= 131072 + ihBytes;

    if (direct) {
        // inpF in ws; gi computed in-register inside the scan -> no giF tensor.
        f16* inpF = (f16*)((char*)d_ws + 131072);
        k_norm<<<dim3(B_), dim3(256), 0, stream>>>(
            cov, tr, oc, g_t, bt, g_o, bo, g_c, bc, Wih, bih, bhh, inpF, WAf, biasF);
        k_scan_f<<<dim3(B_ / R_), dim3(512), 0, stream>>>(
            inpF, WAf, biasF, Whh, bhh, outA, outB);
    } else {
        // fallback: inpF at TOP of d_out (dead before serial scan writes reach it),
        // giF in ws with batch split.
        f16* inpF = (f16*)((char*)d_out + (outBytes - ihBytes));
        f16* giF  = (f16*)((char*)d_ws + 131072);
        k_norm<<<dim3(B_), dim3(256), 0, stream>>>(
            cov, tr, oc, g_t, bt, g_o, bo, g_c, bc, Wih, bih, bhh, inpF, WAf, biasF);
        int S = 8;
        const int cand[4] = {1, 2, 4, 8};
        for (int i = 0; i < 4; i++) {
            size_t need = 131072 + ((size_t)B_ / cand[i]) * L_ * G3 * 2;
            if (need <= ws_size) { S = cand[i]; break; }
        }
        int Bs = B_ / S;
        for (int s = 0; s < S; s++) {
            const f16* Asub = inpF + (size_t)s * Bs * L_ * 1536;
            k_gemm<<<dim3((Bs / 16) * 128), dim3(256), 0, stream>>>(Asub, WAf, biasF, giF);
            k_scan<<<dim3(Bs / R_), dim3(512), 0, stream>>>(giF, Whh, bhh, outA, outB, s * Bs);
        }
    }
}

// Round 13
// 406.466 us; speedup vs baseline: 1.0182x; 1.0182x over previous
//
#include <hip/hip_runtime.h>

typedef _Float16 f16;
typedef _Float16 f16x8 __attribute__((ext_vector_type(8)));
typedef _Float16 f16x4 __attribute__((ext_vector_type(4)));
typedef float f32x4 __attribute__((ext_vector_type(4)));

#define B_ 512
#define L_ 512
#define Cc_ 64
#define Ct_ 16
#define Co_ 8
#define H_ 128
#define IN_ 88
#define KP 96       // padded K for MFMA
#define G3 384      // 3*H
#define R_ 16       // batch rows per scan block / gemm tile

#define L2E  1.44269504088896f   // log2(e)
#define L2E2 2.88539008177793f   // 2*log2(e)

// Fragment-ordered x: inpF[bg][l][ks=0..2][c*4+q][j=0..7] (f16), 1536 f16 per (bg,l).
//   B-frag element (batch c, k=32ks+8q+j). Norm block (batch b) writes 64B chunks
//   (q=0..3 contiguous); scan/gemm wave reads 1KB contiguous per ks.

// ---------------- K1: prep (blocks 0..145) + time-norm + concat -> inpF ------------------
__global__ __launch_bounds__(256) void k_norm(
        const float* __restrict__ cov, const float* __restrict__ tr, const float* __restrict__ oc,
        const float* __restrict__ g_t, const float* __restrict__ bt,
        const float* __restrict__ g_o, const float* __restrict__ bo,
        const float* __restrict__ g_c, const float* __restrict__ bc,
        const float* __restrict__ Wih, const float* __restrict__ bih,
        const float* __restrict__ bhh,
        f16* __restrict__ inpF, f16* __restrict__ WAf, float* __restrict__ biasF) {
    int b = blockIdx.x, t = threadIdx.x;

    // ---- merged k_prep: W_ih -> A-fragment order (scaled); bias (b_hh folded, scaled) ----
    if (b < 146) {
        int idx = b * 256 + t;
        if (idx < G3 * KP) {                       // 36864 WAf elements
            int n0 = idx / 1536;
            int rem = idx - n0 * 1536;
            int ks = rem >> 9;
            int rem2 = rem & 511;
            int lane = rem2 >> 3, j = rem2 & 7;
            int unit = n0 * 16 + (lane & 15);
            int k = ((lane >> 4) << 3) + 32 * ks + j;
            float s = (n0 < 16) ? L2E : L2E2;
            WAf[idx] = (k < IN_) ? (f16)(Wih[unit * IN_ + k] * s) : (f16)0.f;
        } else if (idx < G3 * KP + G3) {           // 384 biases (unit-indexed)
            int u = idx - G3 * KP;
            biasF[u] = (u < 256) ? (bih[u] + bhh[u]) * L2E : bih[u] * L2E2;
        }
    }

    __shared__ float ps[256], ps2[256];
    __shared__ float sc[88], sh[88];   // concat order: t[0:16), o[16:24), c[24:88)

    { // covariates, C=64, 4 l-groups
        int c = t & 63, lg = t >> 6;
        const float* p = cov + (size_t)b * L_ * Cc_ + c;
        float s = 0.f, s2 = 0.f;
        for (int i = lg; i < L_; i += 4) { float v = p[(size_t)i * Cc_]; s += v; s2 += v * v; }
        ps[t] = s; ps2[t] = s2; __syncthreads();
        if (t < 64) {
            float S = 0.f, S2 = 0.f;
            for (int g = 0; g < 4; g++) { S += ps[t + 64 * g]; S2 += ps2[t + 64 * g]; }
            float m = S * (1.f / L_), v = S2 * (1.f / L_) - m * m;
            float inv = rsqrtf(v + 1e-5f);
            float gg = g_c[t] * inv;
            sc[24 + t] = gg; sh[24 + t] = bc[t] - m * gg;
        }
        __syncthreads();
    }
    { // treatments, C=16, 16 l-groups
        int c = t & 15, lg = t >> 4;
        const float* p = tr + (size_t)b * L_ * Ct_ + c;
        float s = 0.f, s2 = 0.f;
        for (int i = lg; i < L_; i += 16) { float v = p[(size_t)i * Ct_]; s += v; s2 += v * v; }
        ps[t] = s; ps2[t] = s2; __syncthreads();
        if (t < 16) {
            float S = 0.f, S2 = 0.f;
            for (int g = 0; g < 16; g++) { S += ps[t + 16 * g]; S2 += ps2[t + 16 * g]; }
            float m = S * (1.f / L_), v = S2 * (1.f / L_) - m * m;
            float inv = rsqrtf(v + 1e-5f);
            float gg = g_t[t] * inv;
            sc[t] = gg; sh[t] = bt[t] - m * gg;
        }
        __syncthreads();
    }
    { // outcomes, C=8, 32 l-groups
        int c = t & 7, lg = t >> 3;
        const float* p = oc + (size_t)b * L_ * Co_ + c;
        float s = 0.f, s2 = 0.f;
        for (int i = lg; i < L_; i += 32) { float v = p[(size_t)i * Co_]; s += v; s2 += v * v; }
        ps[t] = s; ps2[t] = s2; __syncthreads();
        if (t < 8) {
            float S = 0.f, S2 = 0.f;
            for (int g = 0; g < 32; g++) { S += ps[t + 8 * g]; S2 += ps2[t + 8 * g]; }
            float m = S * (1.f / L_), v = S2 * (1.f / L_) - m * m;
            float inv = rsqrtf(v + 1e-5f);
            float gg = g_o[t] * inv;
            sc[16 + t] = gg; sh[16 + t] = bo[t] - m * gg;
        }
        __syncthreads();
    }
    // phase B (vectorized): thread-iter = (l, f); 8 consecutive channels k0 = 8f.
    // Concat boundaries (16, 24) are multiples of 8 -> each chunk is single-source.
    // 2x float4 loads + 1 f16x8 store. Write: [l][ks=f>>2][ (b&15)*4 + (f&3) ][8].
    const int cq = b & 15;
    f16* outp = inpF + (size_t)(b >> 4) * L_ * 1536;
    for (int idx = t; idx < L_ * 12; idx += 256) {
        int l = idx / 12, f = idx - l * 12;
        int k0 = f * 8;
        f16x8 st;
        #pragma unroll
        for (int j = 0; j < 8; j++) st[j] = (f16)0.f;
        if (k0 < IN_) {
            const float* src;
            if (k0 < 16)      src = tr  + ((size_t)b * L_ + l) * Ct_ + k0;
            else if (k0 < 24) src = oc  + ((size_t)b * L_ + l) * Co_ + (k0 - 16);
            else              src = cov + ((size_t)b * L_ + l) * Cc_ + (k0 - 24);
            f32x4 v0 = *(const f32x4*)(src);
            f32x4 v1 = *(const f32x4*)(src + 4);
            #pragma unroll
            for (int j = 0; j < 4; j++) st[j]     = (f16)(v0[j] * sc[k0 + j]     + sh[k0 + j]);
            #pragma unroll
            for (int j = 0; j < 4; j++) st[4 + j] = (f16)(v1[j] * sc[k0 + 4 + j] + sh[k0 + 4 + j]);
        }
        int ks = f >> 2, q = f & 3;
        *(f16x8*)(outp + ((size_t)l * 3 + ks) * 512 + (cq * 4 + q) * 8) = st;
    }
}

// ============== FUSED SCAN: gi computed in-register (no giF tensor at all). ==============
// One block = 16 batch rows, 8 waves (2/SIMD). Wave w owns units [16w,16w+16) of each
// gate. acc chain: acc = bias; acc += W_ih x (3 MFMA); acc += W_hh h (4 MFMA).
// x-loads now wave-contiguous 1KB (fragment-ordered inpF).
__global__ __launch_bounds__(512, 1) void k_scan_f(
        const f16* __restrict__ inpF, const f16* __restrict__ WAf,
        const float* __restrict__ biasF,
        const float* __restrict__ Whh, const float* __restrict__ bhh,
        float* __restrict__ outA, float* __restrict__ outB) {
    const int t = threadIdx.x;
    const int w = t >> 6;          // wave 0..7
    const int lane = t & 63;
    const int c = lane & 15;       // batch row within tile
    const int q = lane >> 4;       // 0..3
    const int q8 = q * 8;
    const int uD = 16 * w + 4 * q; // unit base within a gate block
    const int bg = blockIdx.x;     // batch group (16 rows)

    __shared__ f16 hb0[R_ * H_];   // 4KB each, swizzled [b][k^((b&15)<<3)]
    __shared__ f16 hb1[R_ * H_];

    // persistent W_hh A-fragments: unit = 16w + c, k = q8 + 32ks + j  (f32 -> f16, scaled)
    f16x8 WA[3][4];
    #pragma unroll
    for (int g = 0; g < 3; g++) {
        float s = (g < 2) ? L2E : L2E2;
        #pragma unroll
        for (int ks = 0; ks < 4; ks++) {
            const float* wp = Whh + (size_t)(g * H_ + 16 * w + c) * H_ + q8 + 32 * ks;
            f16x8 v;
            #pragma unroll
            for (int j = 0; j < 8; j++) v[j] = (f16)(wp[j] * s);
            WA[g][ks] = v;
        }
    }
    // persistent W_ih A-fragments (pre-scaled in WAf): tiles n0 = g*8 + w, ks = 0..2
    const f16x8* wa8 = (const f16x8*)WAf;
    f16x8 WI[3][3];
    #pragma unroll
    for (int g = 0; g < 3; g++)
        #pragma unroll
        for (int ks = 0; ks < 3; ks++)
            WI[g][ks] = wa8[(size_t)((g * 8 + w) * 3 + ks) * 64 + lane];

    // per-lane accumulator-init biases (unit-indexed n0*16 + 4q)
    const f32x4 bR   = *(const f32x4*)(biasF + (0 * 8 + w) * 16 + 4 * q);
    const f32x4 bZ   = *(const f32x4*)(biasF + (1 * 8 + w) * 16 + 4 * q);
    const f32x4 bGn  = *(const f32x4*)(biasF + (2 * 8 + w) * 16 + 4 * q);
    const f32x4 bHn  = { L2E2 * bhh[2 * H_ + uD + 0], L2E2 * bhh[2 * H_ + uD + 1],
                         L2E2 * bhh[2 * H_ + uD + 2], L2E2 * bhh[2 * H_ + uD + 3] };

    for (int i = t; i < R_ * H_; i += 512) hb0[i] = (f16)0.f;
    float hp0 = 0.f, hp1 = 0.f, hp2 = 0.f, hp3 = 0.f;

    // ---- coalesced output staging: thread -> (row, 4 contiguous units) ----
    const int orow = t >> 5;               // 0..15 (block-local row)
    const int oe4  = (t & 31) * 4;         // unit base 0..124
    const int oswz = (orow & 15) << 3;
    const int grow = bg * R_ + orow;
    float* op; size_t ost;
    if (oe4 < Co_) { op = outA + (size_t)grow * L_ * Co_ + oe4;            ost = Co_; }
    else           { op = outB + (size_t)grow * L_ * (H_ - Co_) + (oe4 - Co_); ost = H_ - Co_; }

    const int swzm = (c & 15) << 3;             // full-width XOR swizzle (f16 idx bits 3..6)

    // x fragment pointer: fragment-ordered -> 1KB contiguous per (l,ks), 16B per lane
    const f16* xp = inpF + (size_t)bg * L_ * 1536 + (c * 4 + q) * 8;

    // preload x[0] into E buffers
    f16x8 x0e = *(const f16x8*)(xp);
    f16x8 x1e = *(const f16x8*)(xp + 512);
    f16x8 x2e = *(const f16x8*)(xp + 1024);
    f16x8 x0o, x1o, x2o;

    __syncthreads();

#define GRU_STEP(HCUR, HNEXT, X0, X1, X2, DOSTAGE)                                  \
    {                                                                               \
        if (DOSTAGE) {  /* store h_out(prev step), coalesced, f16-rounded */        \
            f16x4 hv = *(const f16x4*)(HCUR + orow * H_ + (oe4 ^ oswz));            \
            f32x4 ov = {(float)hv[0], (float)hv[1], (float)hv[2], (float)hv[3]};    \
            *(f32x4*)op = ov;                                                       \
            op += ost;                                                              \
        }                                                                           \
        f16x8 hB0 = *(const f16x8*)(HCUR + c * H_ + ((q8 +  0) ^ swzm));            \
        f16x8 hB1 = *(const f16x8*)(HCUR + c * H_ + ((q8 + 32) ^ swzm));            \
        f16x8 hB2 = *(const f16x8*)(HCUR + c * H_ + ((q8 + 64) ^ swzm));            \
        f16x8 hB3 = *(const f16x8*)(HCUR + c * H_ + ((q8 + 96) ^ swzm));            \
        f32x4 aR = bR, aZ = bZ, aG = bGn, aH = bHn;                                 \
        /* gi part: x-MFMAs (no hB dependency -> fills DS latency) */               \
        aR = __builtin_amdgcn_mfma_f32_16x16x32_f16(WI[0][0], X0, aR, 0, 0, 0);     \
        aZ = __builtin_amdgcn_mfma_f32_16x16x32_f16(WI[1][0], X0, aZ, 0, 0, 0);     \
        aG = __builtin_amdgcn_mfma_f32_16x16x32_f16(WI[2][0], X0, aG, 0, 0, 0);     \
        aR = __builtin_amdgcn_mfma_f32_16x16x32_f16(WI[0][1], X1, aR, 0, 0, 0);     \
        aZ = __builtin_amdgcn_mfma_f32_16x16x32_f16(WI[1][1], X1, aZ, 0, 0, 0);     \
        aG = __builtin_amdgcn_mfma_f32_16x16x32_f16(WI[2][1], X1, aG, 0, 0, 0);     \
        aR = __builtin_amdgcn_mfma_f32_16x16x32_f16(WI[0][2], X2, aR, 0, 0, 0);     \
        aZ = __builtin_amdgcn_mfma_f32_16x16x32_f16(WI[1][2], X2, aZ, 0, 0, 0);     \
        aG = __builtin_amdgcn_mfma_f32_16x16x32_f16(WI[2][2], X2, aG, 0, 0, 0);     \
        /* h part */                                                                \
        aR = __builtin_amdgcn_mfma_f32_16x16x32_f16(WA[0][0], hB0, aR, 0, 0, 0);    \
        aZ = __builtin_amdgcn_mfma_f32_16x16x32_f16(WA[1][0], hB0, aZ, 0, 0, 0);    \
        aH = __builtin_amdgcn_mfma_f32_16x16x32_f16(WA[2][0], hB0, aH, 0, 0, 0);    \
        aR = __builtin_amdgcn_mfma_f32_16x16x32_f16(WA[0][1], hB1, aR, 0, 0, 0);    \
        aZ = __builtin_amdgcn_mfma_f32_16x16x32_f16(WA[1][1], hB1, aZ, 0, 0, 0);    \
        aH = __builtin_amdgcn_mfma_f32_16x16x32_f16(WA[2][1], hB1, aH, 0, 0, 0);    \
        aR = __builtin_amdgcn_mfma_f32_16x16x32_f16(WA[0][2], hB2, aR, 0, 0, 0);    \
        aZ = __builtin_amdgcn_mfma_f32_16x16x32_f16(WA[1][2], hB2, aZ, 0, 0, 0);    \
        aH = __builtin_amdgcn_mfma_f32_16x16x32_f16(WA[2][2], hB2, aH, 0, 0, 0);    \
        aR = __builtin_amdgcn_mfma_f32_16x16x32_f16(WA[0][3], hB3, aR, 0, 0, 0);    \
        aZ = __builtin_amdgcn_mfma_f32_16x16x32_f16(WA[1][3], hB3, aZ, 0, 0, 0);    \
        aH = __builtin_amdgcn_mfma_f32_16x16x32_f16(WA[2][3], hB3, aH, 0, 0, 0);    \
        float rg0 = __builtin_amdgcn_rcpf(1.f + __builtin_amdgcn_exp2f(-aR[0]));    \
        float rg1 = __builtin_amdgcn_rcpf(1.f + __builtin_amdgcn_exp2f(-aR[1]));    \
        float rg2 = __builtin_amdgcn_rcpf(1.f + __builtin_amdgcn_exp2f(-aR[2]));    \
        float rg3 = __builtin_amdgcn_rcpf(1.f + __builtin_amdgcn_exp2f(-aR[3]));    \
        float zg0 = __builtin_amdgcn_rcpf(1.f + __builtin_amdgcn_exp2f(-aZ[0]));    \
        float zg1 = __builtin_amdgcn_rcpf(1.f + __builtin_amdgcn_exp2f(-aZ[1]));    \
        float zg2 = __builtin_amdgcn_rcpf(1.f + __builtin_amdgcn_exp2f(-aZ[2]));    \
        float zg3 = __builtin_amdgcn_rcpf(1.f + __builtin_amdgcn_exp2f(-aZ[3]));    \
        float tn0 = fmaf(rg0, aH[0], aG[0]);                                        \
        float tn1 = fmaf(rg1, aH[1], aG[1]);                                        \
        float tn2 = fmaf(rg2, aH[2], aG[2]);                                        \
        float tn3 = fmaf(rg3, aH[3], aG[3]);                                        \
        float ng0 = fmaf(2.f, __builtin_amdgcn_rcpf(1.f + __builtin_amdgcn_exp2f(-tn0)), -1.f); \
        float ng1 = fmaf(2.f, __builtin_amdgcn_rcpf(1.f + __builtin_amdgcn_exp2f(-tn1)), -1.f); \
        float ng2 = fmaf(2.f, __builtin_amdgcn_rcpf(1.f + __builtin_amdgcn_exp2f(-tn2)), -1.f); \
        float ng3 = fmaf(2.f, __builtin_amdgcn_rcpf(1.f + __builtin_amdgcn_exp2f(-tn3)), -1.f); \
        hp0 = fmaf(zg0, hp0 - ng0, ng0);                                            \
        hp1 = fmaf(zg1, hp1 - ng1, ng1);                                            \
        hp2 = fmaf(zg2, hp2 - ng2, ng2);                                            \
        hp3 = fmaf(zg3, hp3 - ng3, ng3);                                            \
        f16x4 hv16 = {(f16)hp0, (f16)hp1, (f16)hp2, (f16)hp3};                      \
        *(f16x4*)(HNEXT + c * H_ + (uD ^ swzm)) = hv16;                             \
    }

    for (int l = 0; l < L_; l += 2) {
        // ---- even step l: read hb0, write hb1; prefetch x[l+1] ----
        {
            const f16* xn = xp + (size_t)(l + 1) * 1536;
            x0o = *(const f16x8*)(xn);
            x1o = *(const f16x8*)(xn + 512);
            x2o = *(const f16x8*)(xn + 1024);
        }
        GRU_STEP(hb0, hb1, x0e, x1e, x2e, (l > 0))
        __syncthreads();

        // ---- odd step l+1: read hb1, write hb0; prefetch x[l+2] ----
        {
            int lp = (l + 2 < L_) ? (l + 2) : (L_ - 1);   // clamp: last reload unused
            const f16* xn = xp + (size_t)lp * 1536;
            x0e = *(const f16x8*)(xn);
            x1e = *(const f16x8*)(xn + 512);
            x2e = *(const f16x8*)(xn + 1024);
        }
        GRU_STEP(hb1, hb0, x0o, x1o, x2o, true)
        __syncthreads();
    }
#undef GRU_STEP

    // final output: h_out(L-1) sits in hb0, barrier already passed
    {
        f16x4 hv = *(const f16x4*)(hb0 + orow * H_ + (oe4 ^ oswz));
        f32x4 ov = {(float)hv[0], (float)hv[1], (float)hv[2], (float)hv[3]};
        *(f32x4*)op = ov;
    }
}

// ============== FALLBACK path (small ws): gemm + gi-reading scan. ==============
__global__ __launch_bounds__(256) void k_gemm(
        const f16* __restrict__ inpF, const f16* __restrict__ WAf,
        const float* __restrict__ biasF, f16* __restrict__ giF) {
    const int g0 = blockIdx.x >> 7;
    const int l  = ((blockIdx.x & 127) << 2) + (threadIdx.x >> 6);
    const int lane = threadIdx.x & 63;
    const int c = lane & 15, q = lane >> 4;
    const f16* bp = inpF + ((size_t)g0 * L_ + l) * 1536 + (c * 4 + q) * 8;
    f16x8 x0 = *(const f16x8*)(bp);
    f16x8 x1 = *(const f16x8*)(bp + 512);
    f16x8 x2 = *(const f16x8*)(bp + 1024);
    const f16x8* wa = (const f16x8*)WAf;
    f16* gout = giF + ((size_t)g0 * L_ + l) * 6144 + q * 64 + c * 4;
    #pragma unroll 4
    for (int n0 = 0; n0 < 24; n0++) {
        f16x8 a0 = wa[(n0 * 3 + 0) * 64 + lane];
        f16x8 a1 = wa[(n0 * 3 + 1) * 64 + lane];
        f16x8 a2 = wa[(n0 * 3 + 2) * 64 + lane];
        f32x4 acc = *(const f32x4*)(biasF + n0 * 16 + q * 4);
        acc = __builtin_amdgcn_mfma_f32_16x16x32_f16(a0, x0, acc, 0, 0, 0);
        acc = __builtin_amdgcn_mfma_f32_16x16x32_f16(a1, x1, acc, 0, 0, 0);
        acc = __builtin_amdgcn_mfma_f32_16x16x32_f16(a2, x2, acc, 0, 0, 0);
        f16x4 st = {(f16)acc[0], (f16)acc[1], (f16)acc[2], (f16)acc[3]};
        *(f16x4*)(gout + n0 * 256) = st;
    }
}

__global__ __launch_bounds__(512, 2) void k_scan(
        const f16* __restrict__ giF, const float* __restrict__ Whh,
        const float* __restrict__ bhh, float* __restrict__ outA, float* __restrict__ outB,
        int rowBase) {
    const int t = threadIdx.x;
    const int w = t >> 6;
    const int lane = t & 63;
    const int c = lane & 15;
    const int q = lane >> 4;
    const int q8 = q * 8;
    const int uD = 16 * w + q * 4;
    __shared__ f16 hb0[R_ * H_];
    __shared__ f16 hb1[R_ * H_];
    f16x8 WA[3][4];
    #pragma unroll
    for (int g = 0; g < 3; g++) {
        float s = (g < 2) ? L2E : L2E2;
        #pragma unroll
        for (int ks = 0; ks < 4; ks++) {
            const float* wp = Whh + (size_t)(g * H_ + 16 * w + c) * H_ + q8 + 32 * ks;
            f16x8 v;
            #pragma unroll
            for (int j = 0; j < 8; j++) v[j] = (f16)(wp[j] * s);
            WA[g][ks] = v;
        }
    }
    const f32x4 bN = { L2E2 * bhh[2 * H_ + uD + 0], L2E2 * bhh[2 * H_ + uD + 1],
                       L2E2 * bhh[2 * H_ + uD + 2], L2E2 * bhh[2 * H_ + uD + 3] };
    for (int i = t; i < R_ * H_; i += 512) hb0[i] = (f16)0.f;
    float hp0 = 0.f, hp1 = 0.f, hp2 = 0.f, hp3 = 0.f;
    const int orow = t >> 5;
    const int oe4  = (t & 31) * 4;
    const int oswz = (orow & 15) << 3;
    const int grow = rowBase + blockIdx.x * R_ + orow;
    float* op; size_t ost;
    if (oe4 < Co_) { op = outA + (size_t)grow * L_ * Co_ + oe4;            ost = Co_; }
    else           { op = outB + (size_t)grow * L_ * (H_ - Co_) + (oe4 - Co_); ost = H_ - Co_; }
    const int swzm = (c & 15) << 3;
    const f16* gbase = giF + (size_t)blockIdx.x * L_ * 24 * 256 + w * 256 + q * 64 + c * 4;
    f16x4 gRe = *(const f16x4*)(gbase + 0 * 2048);
    f16x4 gZe = *(const f16x4*)(gbase + 1 * 2048);
    f16x4 gNe = *(const f16x4*)(gbase + 2 * 2048);
    f16x4 gRo, gZo, gNo;
    __syncthreads();
#define GRU_STEP(HCUR, HNEXT, GR, GZ, GN, DOSTAGE)                                  \
    {                                                                               \
        if (DOSTAGE) {                                                              \
            f16x4 hv = *(const f16x4*)(HCUR + orow * H_ + (oe4 ^ oswz));            \
            f32x4 ov = {(float)hv[0], (float)hv[1], (float)hv[2], (float)hv[3]};    \
            *(f32x4*)op = ov;                                                       \
            op += ost;                                                              \
        }                                                                           \
        f16x8 hB0 = *(const f16x8*)(HCUR + c * H_ + ((q8 +  0) ^ swzm));            \
        f16x8 hB1 = *(const f16x8*)(HCUR + c * H_ + ((q8 + 32) ^ swzm));            \
        f16x8 hB2 = *(const f16x8*)(HCUR + c * H_ + ((q8 + 64) ^ swzm));            \
        f16x8 hB3 = *(const f16x8*)(HCUR + c * H_ + ((q8 + 96) ^ swzm));            \
        f32x4 aR = {(float)GR[0], (float)GR[1], (float)GR[2], (float)GR[3]};        \
        f32x4 aZ = {(float)GZ[0], (float)GZ[1], (float)GZ[2], (float)GZ[3]};        \
        f32x4 aN = bN;                                                              \
        aR = __builtin_amdgcn_mfma_f32_16x16x32_f16(WA[0][0], hB0, aR, 0, 0, 0);    \
        aZ = __builtin_amdgcn_mfma_f32_16x16x32_f16(WA[1][0], hB0, aZ, 0, 0, 0);    \
        aN = __builtin_amdgcn_mfma_f32_16x16x32_f16(WA[2][0], hB0, aN, 0, 0, 0);    \
        aR = __builtin_amdgcn_mfma_f32_16x16x32_f16(WA[0][1], hB1, aR, 0, 0, 0);    \
        aZ = __builtin_amdgcn_mfma_f32_16x16x32_f16(WA[1][1], hB1, aZ, 0, 0, 0);    \
        aN = __builtin_amdgcn_mfma_f32_16x16x32_f16(WA[2][1], hB1, aN, 0, 0, 0);    \
        aR = __builtin_amdgcn_mfma_f32_16x16x32_f16(WA[0][2], hB2, aR, 0, 0, 0);    \
        aZ = __builtin_amdgcn_mfma_f32_16x16x32_f16(WA[1][2], hB2, aZ, 0, 0, 0);    \
        aN = __builtin_amdgcn_mfma_f32_16x16x32_f16(WA[2][2], hB2, aN, 0, 0, 0);    \
        aR = __builtin_amdgcn_mfma_f32_16x16x32_f16(WA[0][3], hB3, aR, 0, 0, 0);    \
        aZ = __builtin_amdgcn_mfma_f32_16x16x32_f16(WA[1][3], hB3, aZ, 0, 0, 0);    \
        aN = __builtin_amdgcn_mfma_f32_16x16x32_f16(WA[2][3], hB3, aN, 0, 0, 0);    \
        float rg0 = __builtin_amdgcn_rcpf(1.f + __builtin_amdgcn_exp2f(-aR[0]));    \
        float rg1 = __builtin_amdgcn_rcpf(1.f + __builtin_amdgcn_exp2f(-aR[1]));    \
        float rg2 = __builtin_amdgcn_rcpf(1.f + __builtin_amdgcn_exp2f(-aR[2]));    \
        float rg3 = __builtin_amdgcn_rcpf(1.f + __builtin_amdgcn_exp2f(-aR[3]));    \
        float zg0 = __builtin_amdgcn_rcpf(1.f + __builtin_amdgcn_exp2f(-aZ[0]));    \
        float zg1 = __builtin_amdgcn_rcpf(1.f + __builtin_amdgcn_exp2f(-aZ[1]));    \
        float zg2 = __builtin_amdgcn_rcpf(1.f + __builtin_amdgcn_exp2f(-aZ[2]));    \
        float zg3 = __builtin_amdgcn_rcpf(1.f + __builtin_amdgcn_exp2f(-aZ[3]));    \
        float tn0 = fmaf(rg0, aN[0], (float)GN[0]);                                 \
        float tn1 = fmaf(rg1, aN[1], (float)GN[1]);                                 \
        float tn2 = fmaf(rg2, aN[2], (float)GN[2]);                                 \
        float tn3 = fmaf(rg3, aN[3], (float)GN[3]);                                 \
        float ng0 = fmaf(2.f, __builtin_amdgcn_rcpf(1.f + __builtin_amdgcn_exp2f(-tn0)), -1.f); \
        float ng1 = fmaf(2.f, __builtin_amdgcn_rcpf(1.f + __builtin_amdgcn_exp2f(-tn1)), -1.f); \
        float ng2 = fmaf(2.f, __builtin_amdgcn_rcpf(1.f + __builtin_amdgcn_exp2f(-tn2)), -1.f); \
        float ng3 = fmaf(2.f, __builtin_amdgcn_rcpf(1.f + __builtin_amdgcn_exp2f(-tn3)), -1.f); \
        hp0 = fmaf(zg0, hp0 - ng0, ng0);                                            \
        hp1 = fmaf(zg1, hp1 - ng1, ng1);                                            \
        hp2 = fmaf(zg2, hp2 - ng2, ng2);                                            \
        hp3 = fmaf(zg3, hp3 - ng3, ng3);                                            \
        f16x4 hv16 = {(f16)hp0, (f16)hp1, (f16)hp2, (f16)hp3};                      \
        *(f16x4*)(HNEXT + c * H_ + (uD ^ swzm)) = hv16;                             \
    }
    for (int l = 0; l < L_; l += 2) {
        {
            const f16* gn = gbase + (size_t)(l + 1) * 6144;
            gRo = *(const f16x4*)(gn + 0 * 2048);
            gZo = *(const f16x4*)(gn + 1 * 2048);
            gNo = *(const f16x4*)(gn + 2 * 2048);
        }
        GRU_STEP(hb0, hb1, gRe, gZe, gNe, (l > 0))
        __syncthreads();
        {
            int lp = (l + 2 < L_) ? (l + 2) : (L_ - 1);
            const f16* gn = gbase + (size_t)lp * 6144;
            gRe = *(const f16x4*)(gn + 0 * 2048);
            gZe = *(const f16x4*)(gn + 1 * 2048);
            gNe = *(const f16x4*)(gn + 2 * 2048);
        }
        GRU_STEP(hb1, hb0, gRo, gZo, gNo, true)
        __syncthreads();
    }
#undef GRU_STEP
    {
        f16x4 hv = *(const f16x4*)(hb0 + orow * H_ + (oe4 ^ oswz));
        f32x4 ov = {(float)hv[0], (float)hv[1], (float)hv[2], (float)hv[3]};
        *(f32x4*)op = ov;
    }
}

// ---------------- launch ----------------
extern "C" void kernel_launch(void* const* d_in, const int* in_sizes, int n_in,
                              void* d_out, int out_size, void* d_ws, size_t ws_size,
                              hipStream_t stream) {
    (void)in_sizes; (void)n_in;
    const float* cov = (const float*)d_in[0];
    const float* tr  = (const float*)d_in[1];
    const float* oc  = (const float*)d_in[2];
    const float* Wih = (const float*)d_in[3];
    const float* Whh = (const float*)d_in[4];
    const float* bih = (const float*)d_in[5];
    const float* bhh = (const float*)d_in[6];
    const float* g_t = (const float*)d_in[7];
    const float* bt  = (const float*)d_in[8];
    const float* g_o = (const float*)d_in[9];
    const float* bo  = (const float*)d_in[10];
    const float* g_c = (const float*)d_in[11];
    const float* bc  = (const float*)d_in[12];

    float* outA = (float*)d_out;
    float* outB = (float*)d_out + (size_t)B_ * L_ * Co_;

    // workspace: [WAf 72KB | biasF 1.5KB | pad to 128KB | inpF 50.3MB (direct) / giF (fallback)]
    f16*   WAf   = (f16*)d_ws;
    float* biasF = (float*)((char*)d_ws + 73728);

    size_t outBytes = (size_t)out_size * 4;
    size_t ihBytes  = (size_t)B_ * L_ * KP * 2;        // 50.3 MB

    bool direct = ws_size >= 131072 + ihBytes;

    if (direct) {
        // inpF in ws; gi computed in-register inside the scan -> no giF tensor.
        f16* inpF = (f16*)((char*)d_ws + 131072);
        k_norm<<<dim3(B_), dim3(256), 0, stream>>>(
            cov, tr, oc, g_t, bt, g_o, bo, g_c, bc, Wih, bih, bhh, inpF, WAf, biasF);
        k_scan_f<<<dim3(B_ / R_), dim3(512), 0, stream>>>(
            inpF, WAf, biasF, Whh, bhh, outA, outB);
    } else {
        // fallback: inpF at TOP of d_out (dead before serial scan writes reach it),
        // giF in ws with batch split.
        f16* inpF = (f16*)((char*)d_out + (outBytes - ihBytes));
        f16* giF  = (f16*)((char*)d_ws + 131072);
        k_norm<<<dim3(B_), dim3(256), 0, stream>>>(
            cov, tr, oc, g_t, bt, g_o, bo, g_c, bc, Wih, bih, bhh, inpF, WAf, biasF);
        int S = 8;
        const int cand[4] = {1, 2, 4, 8};
        for (int i = 0; i < 4; i++) {
            size_t need = 131072 + ((size_t)B_ / cand[i]) * L_ * G3 * 2;
            if (need <= ws_size) { S = cand[i]; break; }
        }
        int Bs = B_ / S;
        for (int s = 0; s < S; s++) {
            const f16* Asub = inpF + (size_t)s * Bs * L_ * 1536;
            k_gemm<<<dim3((Bs / 16) * 128), dim3(256), 0, stream>>>(Asub, WAf, biasF, giF);
            k_scan<<<dim3(Bs / R_), dim3(512), 0, stream>>>(giF, Whh, bhh, outA, outB, s * Bs);
        }
    }
}

// Round 14
// 384.288 us; speedup vs baseline: 1.0770x; 1.0577x over previous
//
#include <hip/hip_runtime.h>

typedef _Float16 f16;
typedef _Float16 f16x8 __attribute__((ext_vector_type(8)));
typedef _Float16 f16x4 __attribute__((ext_vector_type(4)));
typedef float f32x4 __attribute__((ext_vector_type(4)));

#define B_ 512
#define L_ 512
#define Cc_ 64
#define Ct_ 16
#define Co_ 8
#define H_ 128
#define IN_ 88
#define KP 96       // padded K for MFMA
#define G3 384      // 3*H
#define R_ 16       // batch rows per scan block / gemm tile

#define L2E  1.44269504088896f   // log2(e)
#define L2E2 2.88539008177793f   // 2*log2(e)

// LDS-only barrier for the scan loop: drains ds ops (lgkmcnt) but NOT vmcnt —
// output-store acks and x-prefetch loads stay in flight across the barrier.
// R7's version also had sched_barrier(0) (scheduler pin) -> regressed; this one
// uses only compiler reorder fences (empty asm), leaving the scheduler free.
#define BARLDS() do { asm volatile("s_waitcnt lgkmcnt(0)" ::: "memory"); \
                      __builtin_amdgcn_s_barrier();                      \
                      asm volatile("" ::: "memory"); } while (0)

// Fragment-ordered x: inpF[bg][l][ks=0..2][c*4+q][j=0..7] (f16), 1536 f16 per (bg,l).

// ---------------- K1: prep (blocks 0..145) + time-norm + concat -> inpF ------------------
__global__ __launch_bounds__(256) void k_norm(
        const float* __restrict__ cov, const float* __restrict__ tr, const float* __restrict__ oc,
        const float* __restrict__ g_t, const float* __restrict__ bt,
        const float* __restrict__ g_o, const float* __restrict__ bo,
        const float* __restrict__ g_c, const float* __restrict__ bc,
        const float* __restrict__ Wih, const float* __restrict__ bih,
        const float* __restrict__ bhh,
        f16* __restrict__ inpF, f16* __restrict__ WAf, float* __restrict__ biasF) {
    int b = blockIdx.x, t = threadIdx.x;

    // ---- merged k_prep: W_ih -> A-fragment order (scaled); bias (b_hh folded, scaled) ----
    if (b < 146) {
        int idx = b * 256 + t;
        if (idx < G3 * KP) {                       // 36864 WAf elements
            int n0 = idx / 1536;
            int rem = idx - n0 * 1536;
            int ks = rem >> 9;
            int rem2 = rem & 511;
            int lane = rem2 >> 3, j = rem2 & 7;
            int unit = n0 * 16 + (lane & 15);
            int k = ((lane >> 4) << 3) + 32 * ks + j;
            float s = (n0 < 16) ? L2E : L2E2;
            WAf[idx] = (k < IN_) ? (f16)(Wih[unit * IN_ + k] * s) : (f16)0.f;
        } else if (idx < G3 * KP + G3) {           // 384 biases (unit-indexed)
            int u = idx - G3 * KP;
            biasF[u] = (u < 256) ? (bih[u] + bhh[u]) * L2E : bih[u] * L2E2;
        }
    }

    __shared__ float ps[256], ps2[256];
    __shared__ float sc[88], sh[88];   // concat order: t[0:16), o[16:24), c[24:88)

    { // covariates, C=64, 4 l-groups
        int c = t & 63, lg = t >> 6;
        const float* p = cov + (size_t)b * L_ * Cc_ + c;
        float s = 0.f, s2 = 0.f;
        for (int i = lg; i < L_; i += 4) { float v = p[(size_t)i * Cc_]; s += v; s2 += v * v; }
        ps[t] = s; ps2[t] = s2; __syncthreads();
        if (t < 64) {
            float S = 0.f, S2 = 0.f;
            for (int g = 0; g < 4; g++) { S += ps[t + 64 * g]; S2 += ps2[t + 64 * g]; }
            float m = S * (1.f / L_), v = S2 * (1.f / L_) - m * m;
            float inv = rsqrtf(v + 1e-5f);
            float gg = g_c[t] * inv;
            sc[24 + t] = gg; sh[24 + t] = bc[t] - m * gg;
        }
        __syncthreads();
    }
    { // treatments, C=16, 16 l-groups
        int c = t & 15, lg = t >> 4;
        const float* p = tr + (size_t)b * L_ * Ct_ + c;
        float s = 0.f, s2 = 0.f;
        for (int i = lg; i < L_; i += 16) { float v = p[(size_t)i * Ct_]; s += v; s2 += v * v; }
        ps[t] = s; ps2[t] = s2; __syncthreads();
        if (t < 16) {
            float S = 0.f, S2 = 0.f;
            for (int g = 0; g < 16; g++) { S += ps[t + 16 * g]; S2 += ps2[t + 16 * g]; }
            float m = S * (1.f / L_), v = S2 * (1.f / L_) - m * m;
            float inv = rsqrtf(v + 1e-5f);
            float gg = g_t[t] * inv;
            sc[t] = gg; sh[t] = bt[t] - m * gg;
        }
        __syncthreads();
    }
    { // outcomes, C=8, 32 l-groups
        int c = t & 7, lg = t >> 3;
        const float* p = oc + (size_t)b * L_ * Co_ + c;
        float s = 0.f, s2 = 0.f;
        for (int i = lg; i < L_; i += 32) { float v = p[(size_t)i * Co_]; s += v; s2 += v * v; }
        ps[t] = s; ps2[t] = s2; __syncthreads();
        if (t < 8) {
            float S = 0.f, S2 = 0.f;
            for (int g = 0; g < 32; g++) { S += ps[t + 8 * g]; S2 += ps2[t + 8 * g]; }
            float m = S * (1.f / L_), v = S2 * (1.f / L_) - m * m;
            float inv = rsqrtf(v + 1e-5f);
            float gg = g_o[t] * inv;
            sc[16 + t] = gg; sh[16 + t] = bo[t] - m * gg;
        }
        __syncthreads();
    }
    // phase B (vectorized): thread-iter = (l, f); 8 consecutive channels k0 = 8f.
    const int cq = b & 15;
    f16* outp = inpF + (size_t)(b >> 4) * L_ * 1536;
    for (int idx = t; idx < L_ * 12; idx += 256) {
        int l = idx / 12, f = idx - l * 12;
        int k0 = f * 8;
        f16x8 st;
        #pragma unroll
        for (int j = 0; j < 8; j++) st[j] = (f16)0.f;
        if (k0 < IN_) {
            const float* src;
            if (k0 < 16)      src = tr  + ((size_t)b * L_ + l) * Ct_ + k0;
            else if (k0 < 24) src = oc  + ((size_t)b * L_ + l) * Co_ + (k0 - 16);
            else              src = cov + ((size_t)b * L_ + l) * Cc_ + (k0 - 24);
            f32x4 v0 = *(const f32x4*)(src);
            f32x4 v1 = *(const f32x4*)(src + 4);
            #pragma unroll
            for (int j = 0; j < 4; j++) st[j]     = (f16)(v0[j] * sc[k0 + j]     + sh[k0 + j]);
            #pragma unroll
            for (int j = 0; j < 4; j++) st[4 + j] = (f16)(v1[j] * sc[k0 + 4 + j] + sh[k0 + 4 + j]);
        }
        int ks = f >> 2, q = f & 3;
        *(f16x8*)(outp + ((size_t)l * 3 + ks) * 512 + (cq * 4 + q) * 8) = st;
    }
}

// ============== FUSED SCAN: gi computed in-register (no giF tensor at all). ==============
__global__ __launch_bounds__(512, 1) void k_scan_f(
        const f16* __restrict__ inpF, const f16* __restrict__ WAf,
        const float* __restrict__ biasF,
        const float* __restrict__ Whh, const float* __restrict__ bhh,
        float* __restrict__ outA, float* __restrict__ outB) {
    const int t = threadIdx.x;
    const int w = t >> 6;          // wave 0..7
    const int lane = t & 63;
    const int c = lane & 15;       // batch row within tile
    const int q = lane >> 4;       // 0..3
    const int q8 = q * 8;
    const int uD = 16 * w + 4 * q; // unit base within a gate block
    const int bg = blockIdx.x;     // batch group (16 rows)

    __shared__ f16 hb0[R_ * H_];   // 4KB each, swizzled [b][k^((b&15)<<3)]
    __shared__ f16 hb1[R_ * H_];

    // persistent W_hh A-fragments: unit = 16w + c, k = q8 + 32ks + j  (f32 -> f16, scaled)
    f16x8 WA[3][4];
    #pragma unroll
    for (int g = 0; g < 3; g++) {
        float s = (g < 2) ? L2E : L2E2;
        #pragma unroll
        for (int ks = 0; ks < 4; ks++) {
            const float* wp = Whh + (size_t)(g * H_ + 16 * w + c) * H_ + q8 + 32 * ks;
            f16x8 v;
            #pragma unroll
            for (int j = 0; j < 8; j++) v[j] = (f16)(wp[j] * s);
            WA[g][ks] = v;
        }
    }
    // persistent W_ih A-fragments (pre-scaled in WAf): tiles n0 = g*8 + w, ks = 0..2
    const f16x8* wa8 = (const f16x8*)WAf;
    f16x8 WI[3][3];
    #pragma unroll
    for (int g = 0; g < 3; g++)
        #pragma unroll
        for (int ks = 0; ks < 3; ks++)
            WI[g][ks] = wa8[(size_t)((g * 8 + w) * 3 + ks) * 64 + lane];

    // per-lane accumulator-init biases (unit-indexed n0*16 + 4q)
    const f32x4 bR   = *(const f32x4*)(biasF + (0 * 8 + w) * 16 + 4 * q);
    const f32x4 bZ   = *(const f32x4*)(biasF + (1 * 8 + w) * 16 + 4 * q);
    const f32x4 bGn  = *(const f32x4*)(biasF + (2 * 8 + w) * 16 + 4 * q);
    const f32x4 bHn  = { L2E2 * bhh[2 * H_ + uD + 0], L2E2 * bhh[2 * H_ + uD + 1],
                         L2E2 * bhh[2 * H_ + uD + 2], L2E2 * bhh[2 * H_ + uD + 3] };

    for (int i = t; i < R_ * H_; i += 512) hb0[i] = (f16)0.f;
    float hp0 = 0.f, hp1 = 0.f, hp2 = 0.f, hp3 = 0.f;

    // ---- coalesced output staging: thread -> (row, 4 contiguous units) ----
    const int orow = t >> 5;               // 0..15 (block-local row)
    const int oe4  = (t & 31) * 4;         // unit base 0..124
    const int oswz = (orow & 15) << 3;
    const int grow = bg * R_ + orow;
    float* op; size_t ost;
    if (oe4 < Co_) { op = outA + (size_t)grow * L_ * Co_ + oe4;            ost = Co_; }
    else           { op = outB + (size_t)grow * L_ * (H_ - Co_) + (oe4 - Co_); ost = H_ - Co_; }

    const int swzm = (c & 15) << 3;             // full-width XOR swizzle (f16 idx bits 3..6)

    // x fragment pointer: fragment-ordered -> 1KB contiguous per (l,ks), 16B per lane
    const f16* xp = inpF + (size_t)bg * L_ * 1536 + (c * 4 + q) * 8;

    // preload x[0] into E buffers
    f16x8 x0e = *(const f16x8*)(xp);
    f16x8 x1e = *(const f16x8*)(xp + 512);
    f16x8 x2e = *(const f16x8*)(xp + 1024);
    f16x8 x0o, x1o, x2o;

    __syncthreads();

#define GRU_STEP(HCUR, HNEXT, X0, X1, X2, DOSTAGE)                                  \
    {                                                                               \
        if (DOSTAGE) {  /* store h_out(prev step), coalesced, f16-rounded */        \
            f16x4 hv = *(const f16x4*)(HCUR + orow * H_ + (oe4 ^ oswz));            \
            f32x4 ov = {(float)hv[0], (float)hv[1], (float)hv[2], (float)hv[3]};    \
            *(f32x4*)op = ov;                                                       \
            op += ost;                                                              \
        }                                                                           \
        f16x8 hB0 = *(const f16x8*)(HCUR + c * H_ + ((q8 +  0) ^ swzm));            \
        f16x8 hB1 = *(const f16x8*)(HCUR + c * H_ + ((q8 + 32) ^ swzm));            \
        f16x8 hB2 = *(const f16x8*)(HCUR + c * H_ + ((q8 + 64) ^ swzm));            \
        f16x8 hB3 = *(const f16x8*)(HCUR + c * H_ + ((q8 + 96) ^ swzm));            \
        f32x4 aR = bR, aZ = bZ, aG = bGn, aH = bHn;                                 \
        /* gi part: x-MFMAs (no hB dependency -> fills DS latency) */               \
        aR = __builtin_amdgcn_mfma_f32_16x16x32_f16(WI[0][0], X0, aR, 0, 0, 0);     \
        aZ = __builtin_amdgcn_mfma_f32_16x16x32_f16(WI[1][0], X0, aZ, 0, 0, 0);     \
        aG = __builtin_amdgcn_mfma_f32_16x16x32_f16(WI[2][0], X0, aG, 0, 0, 0);     \
        aR = __builtin_amdgcn_mfma_f32_16x16x32_f16(WI[0][1], X1, aR, 0, 0, 0);     \
        aZ = __builtin_amdgcn_mfma_f32_16x16x32_f16(WI[1][1], X1, aZ, 0, 0, 0);     \
        aG = __builtin_amdgcn_mfma_f32_16x16x32_f16(WI[2][1], X1, aG, 0, 0, 0);     \
        aR = __builtin_amdgcn_mfma_f32_16x16x32_f16(WI[0][2], X2, aR, 0, 0, 0);     \
        aZ = __builtin_amdgcn_mfma_f32_16x16x32_f16(WI[1][2], X2, aZ, 0, 0, 0);     \
        aG = __builtin_amdgcn_mfma_f32_16x16x32_f16(WI[2][2], X2, aG, 0, 0, 0);     \
        /* h part */                                                                \
        aR = __builtin_amdgcn_mfma_f32_16x16x32_f16(WA[0][0], hB0, aR, 0, 0, 0);    \
        aZ = __builtin_amdgcn_mfma_f32_16x16x32_f16(WA[1][0], hB0, aZ, 0, 0, 0);    \
        aH = __builtin_amdgcn_mfma_f32_16x16x32_f16(WA[2][0], hB0, aH, 0, 0, 0);    \
        aR = __builtin_amdgcn_mfma_f32_16x16x32_f16(WA[0][1], hB1, aR, 0, 0, 0);    \
        aZ = __builtin_amdgcn_mfma_f32_16x16x32_f16(WA[1][1], hB1, aZ, 0, 0, 0);    \
        aH = __builtin_amdgcn_mfma_f32_16x16x32_f16(WA[2][1], hB1, aH, 0, 0, 0);    \
        aR = __builtin_amdgcn_mfma_f32_16x16x32_f16(WA[0][2], hB2, aR, 0, 0, 0);    \
        aZ = __builtin_amdgcn_mfma_f32_16x16x32_f16(WA[1][2], hB2, aZ, 0, 0, 0);    \
        aH = __builtin_amdgcn_mfma_f32_16x16x32_f16(WA[2][2], hB2, aH, 0, 0, 0);    \
        aR = __builtin_amdgcn_mfma_f32_16x16x32_f16(WA[0][3], hB3, aR, 0, 0, 0);    \
        aZ = __builtin_amdgcn_mfma_f32_16x16x32_f16(WA[1][3], hB3, aZ, 0, 0, 0);    \
        aH = __builtin_amdgcn_mfma_f32_16x16x32_f16(WA[2][3], hB3, aH, 0, 0, 0);    \
        float rg0 = __builtin_amdgcn_rcpf(1.f + __builtin_amdgcn_exp2f(-aR[0]));    \
        float rg1 = __builtin_amdgcn_rcpf(1.f + __builtin_amdgcn_exp2f(-aR[1]));    \
        float rg2 = __builtin_amdgcn_rcpf(1.f + __builtin_amdgcn_exp2f(-aR[2]));    \
        float rg3 = __builtin_amdgcn_rcpf(1.f + __builtin_amdgcn_exp2f(-aR[3]));    \
        float zg0 = __builtin_amdgcn_rcpf(1.f + __builtin_amdgcn_exp2f(-aZ[0]));    \
        float zg1 = __builtin_amdgcn_rcpf(1.f + __builtin_amdgcn_exp2f(-aZ[1]));    \
        float zg2 = __builtin_amdgcn_rcpf(1.f + __builtin_amdgcn_exp2f(-aZ[2]));    \
        float zg3 = __builtin_amdgcn_rcpf(1.f + __builtin_amdgcn_exp2f(-aZ[3]));    \
        float tn0 = fmaf(rg0, aH[0], aG[0]);                                        \
        float tn1 = fmaf(rg1, aH[1], aG[1]);                                        \
        float tn2 = fmaf(rg2, aH[2], aG[2]);                                        \
        float tn3 = fmaf(rg3, aH[3], aG[3]);                                        \
        float ng0 = fmaf(2.f, __builtin_amdgcn_rcpf(1.f + __builtin_amdgcn_exp2f(-tn0)), -1.f); \
        float ng1 = fmaf(2.f, __builtin_amdgcn_rcpf(1.f + __builtin_amdgcn_exp2f(-tn1)), -1.f); \
        float ng2 = fmaf(2.f, __builtin_amdgcn_rcpf(1.f + __builtin_amdgcn_exp2f(-tn2)), -1.f); \
        float ng3 = fmaf(2.f, __builtin_amdgcn_rcpf(1.f + __builtin_amdgcn_exp2f(-tn3)), -1.f); \
        hp0 = fmaf(zg0, hp0 - ng0, ng0);                                            \
        hp1 = fmaf(zg1, hp1 - ng1, ng1);                                            \
        hp2 = fmaf(zg2, hp2 - ng2, ng2);                                            \
        hp3 = fmaf(zg3, hp3 - ng3, ng3);                                            \
        f16x4 hv16 = {(f16)hp0, (f16)hp1, (f16)hp2, (f16)hp3};                      \
        *(f16x4*)(HNEXT + c * H_ + (uD ^ swzm)) = hv16;                             \
    }

    for (int l = 0; l < L_; l += 2) {
        // ---- even step l: read hb0, write hb1; prefetch x[l+1] ----
        {
            const f16* xn = xp + (size_t)(l + 1) * 1536;
            x0o = *(const f16x8*)(xn);
            x1o = *(const f16x8*)(xn + 512);
            x2o = *(const f16x8*)(xn + 1024);
        }
        GRU_STEP(hb0, hb1, x0e, x1e, x2e, (l > 0))
        BARLDS();

        // ---- odd step l+1: read hb1, write hb0; prefetch x[l+2] ----
        {
            int lp = (l + 2 < L_) ? (l + 2) : (L_ - 1);   // clamp: last reload unused
            const f16* xn = xp + (size_t)lp * 1536;
            x0e = *(const f16x8*)(xn);
            x1e = *(const f16x8*)(xn + 512);
            x2e = *(const f16x8*)(xn + 1024);
        }
        GRU_STEP(hb1, hb0, x0o, x1o, x2o, true)
        BARLDS();
    }
#undef GRU_STEP

    // final output: h_out(L-1) sits in hb0, barrier already passed
    {
        f16x4 hv = *(const f16x4*)(hb0 + orow * H_ + (oe4 ^ oswz));
        f32x4 ov = {(float)hv[0], (float)hv[1], (float)hv[2], (float)hv[3]};
        *(f32x4*)op = ov;
    }
}

// ============== FALLBACK path (small ws): gemm + gi-reading scan. ==============
__global__ __launch_bounds__(256) void k_gemm(
        const f16* __restrict__ inpF, const f16* __restrict__ WAf,
        const float* __restrict__ biasF, f16* __restrict__ giF) {
    const int g0 = blockIdx.x >> 7;
    const int l  = ((blockIdx.x & 127) << 2) + (threadIdx.x >> 6);
    const int lane = threadIdx.x & 63;
    const int c = lane & 15, q = lane >> 4;
    const f16* bp = inpF + ((size_t)g0 * L_ + l) * 1536 + (c * 4 + q) * 8;
    f16x8 x0 = *(const f16x8*)(bp);
    f16x8 x1 = *(const f16x8*)(bp + 512);
    f16x8 x2 = *(const f16x8*)(bp + 1024);
    const f16x8* wa = (const f16x8*)WAf;
    f16* gout = giF + ((size_t)g0 * L_ + l) * 6144 + q * 64 + c * 4;
    #pragma unroll 4
    for (int n0 = 0; n0 < 24; n0++) {
        f16x8 a0 = wa[(n0 * 3 + 0) * 64 + lane];
        f16x8 a1 = wa[(n0 * 3 + 1) * 64 + lane];
        f16x8 a2 = wa[(n0 * 3 + 2) * 64 + lane];
        f32x4 acc = *(const f32x4*)(biasF + n0 * 16 + q * 4);
        acc = __builtin_amdgcn_mfma_f32_16x16x32_f16(a0, x0, acc, 0, 0, 0);
        acc = __builtin_amdgcn_mfma_f32_16x16x32_f16(a1, x1, acc, 0, 0, 0);
        acc = __builtin_amdgcn_mfma_f32_16x16x32_f16(a2, x2, acc, 0, 0, 0);
        f16x4 st = {(f16)acc[0], (f16)acc[1], (f16)acc[2], (f16)acc[3]};
        *(f16x4*)(gout + n0 * 256) = st;
    }
}

__global__ __launch_bounds__(512, 2) void k_scan(
        const f16* __restrict__ giF, const float* __restrict__ Whh,
        const float* __restrict__ bhh, float* __restrict__ outA, float* __restrict__ outB,
        int rowBase) {
    const int t = threadIdx.x;
    const int w = t >> 6;
    const int lane = t & 63;
    const int c = lane & 15;
    const int q = lane >> 4;
    const int q8 = q * 8;
    const int uD = 16 * w + q * 4;
    __shared__ f16 hb0[R_ * H_];
    __shared__ f16 hb1[R_ * H_];
    f16x8 WA[3][4];
    #pragma unroll
    for (int g = 0; g < 3; g++) {
        float s = (g < 2) ? L2E : L2E2;
        #pragma unroll
        for (int ks = 0; ks < 4; ks++) {
            const float* wp = Whh + (size_t)(g * H_ + 16 * w + c) * H_ + q8 + 32 * ks;
            f16x8 v;
            #pragma unroll
            for (int j = 0; j < 8; j++) v[j] = (f16)(wp[j] * s);
            WA[g][ks] = v;
        }
    }
    const f32x4 bN = { L2E2 * bhh[2 * H_ + uD + 0], L2E2 * bhh[2 * H_ + uD + 1],
                       L2E2 * bhh[2 * H_ + uD + 2], L2E2 * bhh[2 * H_ + uD + 3] };
    for (int i = t; i < R_ * H_; i += 512) hb0[i] = (f16)0.f;
    float hp0 = 0.f, hp1 = 0.f, hp2 = 0.f, hp3 = 0.f;
    const int orow = t >> 5;
    const int oe4  = (t & 31) * 4;
    const int oswz = (orow & 15) << 3;
    const int grow = rowBase + blockIdx.x * R_ + orow;
    float* op; size_t ost;
    if (oe4 < Co_) { op = outA + (size_t)grow * L_ * Co_ + oe4;            ost = Co_; }
    else           { op = outB + (size_t)grow * L_ * (H_ - Co_) + (oe4 - Co_); ost = H_ - Co_; }
    const int swzm = (c & 15) << 3;
    const f16* gbase = giF + (size_t)blockIdx.x * L_ * 24 * 256 + w * 256 + q * 64 + c * 4;
    f16x4 gRe = *(const f16x4*)(gbase + 0 * 2048);
    f16x4 gZe = *(const f16x4*)(gbase + 1 * 2048);
    f16x4 gNe = *(const f16x4*)(gbase + 2 * 2048);
    f16x4 gRo, gZo, gNo;
    __syncthreads();
#define GRU_STEP(HCUR, HNEXT, GR, GZ, GN, DOSTAGE)                                  \
    {                                                                               \
        if (DOSTAGE) {                                                              \
            f16x4 hv = *(const f16x4*)(HCUR + orow * H_ + (oe4 ^ oswz));            \
            f32x4 ov = {(float)hv[0], (float)hv[1], (float)hv[2], (float)hv[3]};    \
            *(f32x4*)op = ov;                                                       \
            op += ost;                                                              \
        }                                                                           \
        f16x8 hB0 = *(const f16x8*)(HCUR + c * H_ + ((q8 +  0) ^ swzm));            \
        f16x8 hB1 = *(const f16x8*)(HCUR + c * H_ + ((q8 + 32) ^ swzm));            \
        f16x8 hB2 = *(const f16x8*)(HCUR + c * H_ + ((q8 + 64) ^ swzm));            \
        f16x8 hB3 = *(const f16x8*)(HCUR + c * H_ + ((q8 + 96) ^ swzm));            \
        f32x4 aR = {(float)GR[0], (float)GR[1], (float)GR[2], (float)GR[3]};        \
        f32x4 aZ = {(float)GZ[0], (float)GZ[1], (float)GZ[2], (float)GZ[3]};        \
        f32x4 aN = bN;                                                              \
        aR = __builtin_amdgcn_mfma_f32_16x16x32_f16(WA[0][0], hB0, aR, 0, 0, 0);    \
        aZ = __builtin_amdgcn_mfma_f32_16x16x32_f16(WA[1][0], hB0, aZ, 0, 0, 0);    \
        aN = __builtin_amdgcn_mfma_f32_16x16x32_f16(WA[2][0], hB0, aN, 0, 0, 0);    \
        aR = __builtin_amdgcn_mfma_f32_16x16x32_f16(WA[0][1], hB1, aR, 0, 0, 0);    \
        aZ = __builtin_amdgcn_mfma_f32_16x16x32_f16(WA[1][1], hB1, aZ, 0, 0, 0);    \
        aN = __builtin_amdgcn_mfma_f32_16x16x32_f16(WA[2][1], hB1, aN, 0, 0, 0);    \
        aR = __builtin_amdgcn_mfma_f32_16x16x32_f16(WA[0][2], hB2, aR, 0, 0, 0);    \
        aZ = __builtin_amdgcn_mfma_f32_16x16x32_f16(WA[1][2], hB2, aZ, 0, 0, 0);    \
        aN = __builtin_amdgcn_mfma_f32_16x16x32_f16(WA[2][2], hB2, aN, 0, 0, 0);    \
        aR = __builtin_amdgcn_mfma_f32_16x16x32_f16(WA[0][3], hB3, aR, 0, 0, 0);    \
        aZ = __builtin_amdgcn_mfma_f32_16x16x32_f16(WA[1][3], hB3, aZ, 0, 0, 0);    \
        aN = __builtin_amdgcn_mfma_f32_16x16x32_f16(WA[2][3], hB3, aN, 0, 0, 0);    \
        float rg0 = __builtin_amdgcn_rcpf(1.f + __builtin_amdgcn_exp2f(-aR[0]));    \
        float rg1 = __builtin_amdgcn_rcpf(1.f + __builtin_amdgcn_exp2f(-aR[1]));    \
        float rg2 = __builtin_amdgcn_rcpf(1.f + __builtin_amdgcn_exp2f(-aR[2]));    \
        float rg3 = __builtin_amdgcn_rcpf(1.f + __builtin_amdgcn_exp2f(-aR[3]));    \
        float zg0 = __builtin_amdgcn_rcpf(1.f + __builtin_amdgcn_exp2f(-aZ[0]));    \
        float zg1 = __builtin_amdgcn_rcpf(1.f + __builtin_amdgcn_exp2f(-aZ[1]));    \
        float zg2 = __builtin_amdgcn_rcpf(1.f + __builtin_amdgcn_exp2f(-aZ[2]));    \
        float zg3 = __builtin_amdgcn_rcpf(1.f + __builtin_amdgcn_exp2f(-aZ[3]));    \
        float tn0 = fmaf(rg0, aN[0], (float)GN[0]);                                 \
        float tn1 = fmaf(rg1, aN[1], (float)GN[1]);                                 \
        float tn2 = fmaf(rg2, aN[2], (float)GN[2]);                                 \
        float tn3 = fmaf(rg3, aN[3], (float)GN[3]);                                 \
        float ng0 = fmaf(2.f, __builtin_amdgcn_rcpf(1.f + __builtin_amdgcn_exp2f(-tn0)), -1.f); \
        float ng1 = fmaf(2.f, __builtin_amdgcn_rcpf(1.f + __builtin_amdgcn_exp2f(-tn1)), -1.f); \
        float ng2 = fmaf(2.f, __builtin_amdgcn_rcpf(1.f + __builtin_amdgcn_exp2f(-tn2)), -1.f); \
        float ng3 = fmaf(2.f, __builtin_amdgcn_rcpf(1.f + __builtin_amdgcn_exp2f(-tn3)), -1.f); \
        hp0 = fmaf(zg0, hp0 - ng0, ng0);                                            \
        hp1 = fmaf(zg1, hp1 - ng1, ng1);                                            \
        hp2 = fmaf(zg2, hp2 - ng2, ng2);                                            \
        hp3 = fmaf(zg3, hp3 - ng3, ng3);                                            \
        f16x4 hv16 = {(f16)hp0, (f16)hp1, (f16)hp2, (f16)hp3};                      \
        *(f16x4*)(HNEXT + c * H_ + (uD ^ swzm)) = hv16;                             \
    }
    for (int l = 0; l < L_; l += 2) {
        {
            const f16* gn = gbase + (size_t)(l + 1) * 6144;
            gRo = *(const f16x4*)(gn + 0 * 2048);
            gZo = *(const f16x4*)(gn + 1 * 2048);
            gNo = *(const f16x4*)(gn + 2 * 2048);
        }
        GRU_STEP(hb0, hb1, gRe, gZe, gNe, (l > 0))
        __syncthreads();
        {
            int lp = (l + 2 < L_) ? (l + 2) : (L_ - 1);
            const f16* gn = gbase + (size_t)lp * 6144;
            gRe = *(const f16x4*)(gn + 0 * 2048);
            gZe = *(const f16x4*)(gn + 1 * 2048);
            gNe = *(const f16x4*)(gn + 2 * 2048);
        }
        GRU_STEP(hb1, hb0, gRo, gZo, gNo, true)
        __syncthreads();
    }
#undef GRU_STEP
    {
        f16x4 hv = *(const f16x4*)(hb0 + orow * H_ + (oe4 ^ oswz));
        f32x4 ov = {(float)hv[0], (float)hv[1], (float)hv[2], (float)hv[3]};
        *(f32x4*)op = ov;
    }
}

// ---------------- launch ----------------
extern "C" void kernel_launch(void* const* d_in, const int* in_sizes, int n_in,
                              void* d_out, int out_size, void* d_ws, size_t ws_size,
                              hipStream_t stream) {
    (void)in_sizes; (void)n_in;
    const float* cov = (const float*)d_in[0];
    const float* tr  = (const float*)d_in[1];
    const float* oc  = (const float*)d_in[2];
    const float* Wih = (const float*)d_in[3];
    const float* Whh = (const float*)d_in[4];
    const float* bih = (const float*)d_in[5];
    const float* bhh = (const float*)d_in[6];
    const float* g_t = (const float*)d_in[7];
    const float* bt  = (const float*)d_in[8];
    const float* g_o = (const float*)d_in[9];
    const float* bo  = (const float*)d_in[10];
    const float* g_c = (const float*)d_in[11];
    const float* bc  = (const float*)d_in[12];

    float* outA = (float*)d_out;
    float* outB = (float*)d_out + (size_t)B_ * L_ * Co_;

    // workspace: [WAf 72KB | biasF 1.5KB | pad to 128KB | inpF 50.3MB (direct) / giF (fallback)]
    f16*   WAf   = (f16*)d_ws;
    float* biasF = (float*)((char*)d_ws + 73728);

    size_t outBytes = (size_t)out_size * 4;
    size_t ihBytes  = (size_t)B_ * L_ * KP * 2;        // 50.3 MB

    bool direct = ws_size >= 131072 + ihBytes;

    if (direct) {
        // inpF in ws; gi computed in-register inside the scan -> no giF tensor.
        f16* inpF = (f16*)((char*)d_ws + 131072);
        k_norm<<<dim3(B_), dim3(256), 0, stream>>>(
            cov, tr, oc, g_t, bt, g_o, bo, g_c, bc, Wih, bih, bhh, inpF, WAf, biasF);
        k_scan_f<<<dim3(B_ / R_), dim3(512), 0, stream>>>(
            inpF, WAf, biasF, Whh, bhh, outA, outB);
    } else {
        // fallback: inpF at TOP of d_out (dead before serial scan writes reach it),
        // giF in ws with batch split.
        f16* inpF = (f16*)((char*)d_out + (outBytes - ihBytes));
        f16* giF  = (f16*)((char*)d_ws + 131072);
        k_norm<<<dim3(B_), dim3(256), 0, stream>>>(
            cov, tr, oc, g_t, bt, g_o, bo, g_c, bc, Wih, bih, bhh, inpF, WAf, biasF);
        int S = 8;
        const int cand[4] = {1, 2, 4, 8};
        for (int i = 0; i < 4; i++) {
            size_t need = 131072 + ((size_t)B_ / cand[i]) * L_ * G3 * 2;
            if (need <= ws_size) { S = cand[i]; break; }
        }
        int Bs = B_ / S;
        for (int s = 0; s < S; s++) {
            const f16* Asub = inpF + (size_t)s * Bs * L_ * 1536;
            k_gemm<<<dim3((Bs / 16) * 128), dim3(256), 0, stream>>>(Asub, WAf, biasF, giF);
            k_scan<<<dim3(Bs / R_), dim3(512), 0, stream>>>(giF, Whh, bhh, outA, outB, s * Bs);
        }
    }
}